// Round 5
// baseline (184.134 us; speedup 1.0000x reference)
//
#include <hip/hip_runtime.h>
#include <hip/hip_bf16.h>
#include <stdint.h>

// SelfAttention: B=4, C=64, H=W=64 -> N=4096 tokens, d=64.
//   q/k/v = W @ x + b (1x1 conv), S = Q K^T (no scale), P = softmax_j(S), out = P V.
// Round 4 was structurally correct but 1.6x over the absmax threshold (precision).
// Round 5: (1) projection made f32-exact via 3-term bf16 hi/lo split MFMA,
//          (2) attention Q/K/V/P in fp16 (8x finer mantissa than bf16), f32 softmax.

#define DIM  64
#define NTOK 4096
#define NB   4

typedef float f32x4 __attribute__((ext_vector_type(4)));
typedef __bf16 bf16x8 __attribute__((ext_vector_type(8)));
typedef _Float16 f16x8 __attribute__((ext_vector_type(8)));
typedef unsigned short u16x8 __attribute__((ext_vector_type(8)));
typedef unsigned short u16x4 __attribute__((ext_vector_type(4)));

__device__ __forceinline__ void gload_lds16(const void* g, void* s) {
  __builtin_amdgcn_global_load_lds(
      (const __attribute__((address_space(1))) void*)g,
      (__attribute__((address_space(3))) void*)s, 16, 0, 0);
}

__device__ __forceinline__ unsigned short f2h(float f) {
  return __builtin_bit_cast(unsigned short, (_Float16)f);
}
__device__ __forceinline__ float h2f(unsigned short u) {
  return (float)__builtin_bit_cast(_Float16, u);
}

// ---------------- QKV projection (f32-accurate via bf16 hi/lo 3-term MFMA) ----------------
// grid = NB * (NTOK/64), block = 256 (4 waves). Block: 64 tokens; wave w: output chans 16w..+15.
// Outputs: Qg,Kg = [b][n][64] fp16, Vg = [b][c][n] fp16.
__global__ __launch_bounds__(256) void qkv_proj(
    const float* __restrict__ x,
    const float* __restrict__ Wq, const float* __restrict__ bq,
    const float* __restrict__ Wk, const float* __restrict__ bk,
    const float* __restrict__ Wv, const float* __restrict__ bv,
    unsigned short* __restrict__ Qg, unsigned short* __restrict__ Kg,
    unsigned short* __restrict__ Vg)
{
  __shared__ __align__(16) float xs[64][68];   // [c][n], pad 68 keeps f32x4 stores aligned
  const int tid = threadIdx.x;
  const int b  = blockIdx.x >> 6;
  const int n0 = (blockIdx.x & 63) << 6;
  const float* xb = x + (size_t)b * DIM * NTOK;

  for (int u = tid; u < 64 * 16; u += 256) {
    int c = u >> 4, q = u & 15;
    *(f32x4*)&xs[c][q * 4] = *(const f32x4*)(xb + (size_t)c * NTOK + n0 + q * 4);
  }
  __syncthreads();

  const int w = tid >> 6, l = tid & 63;
  const int lr = l & 15, lg = l >> 4;
  const int o0 = w << 4;

  // x^T hi/lo fragments: A-frag rows n (Q/K) == B-frag cols n (V). c = ks*32 + lg*8 + e.
  bf16x8 xh[4][2], xl[4][2];
  #pragma unroll
  for (int ns = 0; ns < 4; ns++) {
    #pragma unroll
    for (int ks = 0; ks < 2; ks++) {
      u16x8 uh, ul;
      #pragma unroll
      for (int e = 0; e < 8; e++) {
        float v = xs[ks * 32 + lg * 8 + e][ns * 16 + lr];
        __bf16 h = (__bf16)v;
        uh[e] = __builtin_bit_cast(unsigned short, h);
        ul[e] = __builtin_bit_cast(unsigned short, (__bf16)(v - (float)h));
      }
      xh[ns][ks] = __builtin_bit_cast(bf16x8, uh);
      xl[ns][ks] = __builtin_bit_cast(bf16x8, ul);
    }
  }

  // W hi/lo fragments: row o0+lr, 8 contiguous c. B-frag (W^T) for Q/K, A-frag for V.
  bf16x8 wh[3][2], wl[3][2];
  const float* Wm[3] = {Wq, Wk, Wv};
  #pragma unroll
  for (int m = 0; m < 3; m++) {
    #pragma unroll
    for (int ks = 0; ks < 2; ks++) {
      const float* p = Wm[m] + (o0 + lr) * DIM + ks * 32 + lg * 8;
      u16x8 uh, ul;
      #pragma unroll
      for (int e = 0; e < 8; e++) {
        float v = p[e];
        __bf16 h = (__bf16)v;
        uh[e] = __builtin_bit_cast(unsigned short, h);
        ul[e] = __builtin_bit_cast(unsigned short, (__bf16)(v - (float)h));
      }
      wh[m][ks] = __builtin_bit_cast(bf16x8, uh);
      wl[m][ks] = __builtin_bit_cast(bf16x8, ul);
    }
  }

  const float bqv = bq[o0 + lr], bkv = bk[o0 + lr];
  float bvv[4];
  #pragma unroll
  for (int r = 0; r < 4; r++) bvv[r] = bv[o0 + lg * 4 + r];

  #pragma unroll
  for (int ns = 0; ns < 4; ns++) {
    f32x4 aq = {bqv, bqv, bqv, bqv};
    f32x4 ak = {bkv, bkv, bkv, bkv};
    f32x4 av = {bvv[0], bvv[1], bvv[2], bvv[3]};
    #pragma unroll
    for (int ks = 0; ks < 2; ks++) {
      // (xh+xl)(wh+wl) ~= xh*wh + xh*wl + xl*wh  (dropped xl*wl ~ 2^-16 relative)
      aq = __builtin_amdgcn_mfma_f32_16x16x32_bf16(xh[ns][ks], wh[0][ks], aq, 0, 0, 0);
      aq = __builtin_amdgcn_mfma_f32_16x16x32_bf16(xh[ns][ks], wl[0][ks], aq, 0, 0, 0);
      aq = __builtin_amdgcn_mfma_f32_16x16x32_bf16(xl[ns][ks], wh[0][ks], aq, 0, 0, 0);
      ak = __builtin_amdgcn_mfma_f32_16x16x32_bf16(xh[ns][ks], wh[1][ks], ak, 0, 0, 0);
      ak = __builtin_amdgcn_mfma_f32_16x16x32_bf16(xh[ns][ks], wl[1][ks], ak, 0, 0, 0);
      ak = __builtin_amdgcn_mfma_f32_16x16x32_bf16(xl[ns][ks], wh[1][ks], ak, 0, 0, 0);
      av = __builtin_amdgcn_mfma_f32_16x16x32_bf16(wh[2][ks], xh[ns][ks], av, 0, 0, 0);
      av = __builtin_amdgcn_mfma_f32_16x16x32_bf16(wl[2][ks], xh[ns][ks], av, 0, 0, 0);
      av = __builtin_amdgcn_mfma_f32_16x16x32_bf16(wh[2][ks], xl[ns][ks], av, 0, 0, 0);
    }
    // Q/K tiles: D[row=n][col=o]; lane: o = o0+lr, n = n0+ns*16+4*lg+r
    #pragma unroll
    for (int r = 0; r < 4; r++) {
      int n = n0 + ns * 16 + lg * 4 + r;
      size_t base = ((size_t)b * NTOK + n) * DIM + o0 + lr;
      Qg[base] = f2h(aq[r]);
      Kg[base] = f2h(ak[r]);
    }
    // V tiles: D[row=o][col=n]; lane: n = n0+ns*16+lr, o = o0+4*lg+r
    #pragma unroll
    for (int r = 0; r < 4; r++) {
      int n = n0 + ns * 16 + lr;
      int o = o0 + lg * 4 + r;
      Vg[((size_t)b * DIM + o) * NTOK + n] = f2h(av[r]);
    }
  }
}

// ---------------- Flash attention (fp16 MFMA, f32 softmax) ----------------
// grid = NB * (NTOK/64), block = 256 (4 waves). Wave w owns Q rows i0+16w..+15.
// K/V tiles double-buffered in LDS (XOR chunk-swizzled via pre-swizzled global source).
__global__ __launch_bounds__(256) void attn_fwd(
    const unsigned short* __restrict__ Qg, const unsigned short* __restrict__ Kg,
    const unsigned short* __restrict__ Vg, float* __restrict__ out)
{
  __shared__ __align__(16) unsigned short Ks[2][64 * 64]; // [j][c], chunk-swizzled rows
  __shared__ __align__(16) unsigned short Vs[2][64 * 64]; // [c][j], chunk-swizzled rows
  __shared__ __align__(16) unsigned short Pk[4 * 1056];   // per-wave P: [i_hi:4][j:66pad][i_lo:4]

  const int tid = threadIdx.x;
  const int w = tid >> 6, l = tid & 63;
  const int lr = l & 15, lg = l >> 4;
  const int b  = blockIdx.x >> 6;
  const int i0 = (blockIdx.x & 63) << 6;

  // Q fragments (registers, reused for all 64 K/V tiles)
  f16x8 qf[2];
  {
    const unsigned short* qp = Qg + ((size_t)b * NTOK + i0 + w * 16 + lr) * DIM;
    qf[0] = __builtin_bit_cast(f16x8, *(const u16x8*)(qp + lg * 8));
    qf[1] = __builtin_bit_cast(f16x8, *(const u16x8*)(qp + 32 + lg * 8));
  }

  float m[4], ls[4];
  f32x4 accO[4];
  #pragma unroll
  for (int r = 0; r < 4; r++) { m[r] = -3.0e38f; ls[r] = 0.f; }
  #pragma unroll
  for (int ct = 0; ct < 4; ct++) accO[ct] = (f32x4){0.f, 0.f, 0.f, 0.f};

  auto stage = [&](int t, int d) {
    const int j0 = t << 6;
    #pragma unroll
    for (int s = 0; s < 2; s++) {
      int ch = (w * 2 + s) * 64 + l;          // 16B chunk id within 8KB tile
      int row = ch >> 3, p = ch & 7;          // row + chunk-in-row; swizzle source so
      int ps = p ^ (row & 7);                 // linear LDS dest holds swizzled layout
      const unsigned short* gk = Kg + ((size_t)b * NTOK + j0 + row) * DIM + ps * 8;
      gload_lds16(gk, &Ks[d][(w * 2 + s) * 512]);
      const unsigned short* gv = Vg + ((size_t)b * DIM + row) * NTOK + j0 + ps * 8;
      gload_lds16(gv, &Vs[d][(w * 2 + s) * 512]);
    }
  };

  stage(0, 0);
  __syncthreads();

  for (int t = 0; t < 64; t++) {
    const int d = t & 1;
    if (t < 63) stage(t + 1, d ^ 1);

    // ---- S = Q K^T  (4 j-subtiles x K=64) ----
    f32x4 S[4];
    #pragma unroll
    for (int jt = 0; jt < 4; jt++) {
      f32x4 s = {0.f, 0.f, 0.f, 0.f};
      #pragma unroll
      for (int ks = 0; ks < 2; ks++) {
        int row = jt * 16 + lr;
        int ch = (ks * 4 + lg) ^ (row & 7);
        u16x8 kv = *(const u16x8*)&Ks[d][row * 64 + ch * 8];
        s = __builtin_amdgcn_mfma_f32_16x16x32_f16(qf[ks], __builtin_bit_cast(f16x8, kv), s, 0, 0, 0);
      }
      S[jt] = s;
    }

    // ---- online softmax (rows i = 4*lg + r; reduce over j = lanes lr 0..15) ----
    float mx[4], mn[4], sc[4], rs[4];
    #pragma unroll
    for (int r = 0; r < 4; r++)
      mx[r] = fmaxf(fmaxf(S[0][r], S[1][r]), fmaxf(S[2][r], S[3][r]));
    #pragma unroll
    for (int sh = 8; sh >= 1; sh >>= 1) {
      #pragma unroll
      for (int r = 0; r < 4; r++)
        mx[r] = fmaxf(mx[r], __shfl_xor(mx[r], sh));
    }
    #pragma unroll
    for (int r = 0; r < 4; r++) {
      mn[r] = fmaxf(m[r], mx[r]);
      sc[r] = __expf(m[r] - mn[r]);
      rs[r] = 0.f;
    }
    // P = exp(S - mn), fp16-round, pack 4 rows -> one b64 LDS write per j-subtile
    #pragma unroll
    for (int jt = 0; jt < 4; jt++) {
      u16x4 pb;
      #pragma unroll
      for (int r = 0; r < 4; r++) {
        unsigned short u = f2h(__expf(S[jt][r] - mn[r]));
        pb[r] = u;
        rs[r] += h2f(u);     // sum the rounded P for consistency with PV
      }
      *(u16x4*)&Pk[w * 1056 + lg * 264 + (jt * 16 + lr) * 4] = pb;
    }
    #pragma unroll
    for (int sh = 8; sh >= 1; sh >>= 1) {
      #pragma unroll
      for (int r = 0; r < 4; r++)
        rs[r] += __shfl_xor(rs[r], sh);
    }
    #pragma unroll
    for (int r = 0; r < 4; r++) {
      ls[r] = ls[r] * sc[r] + rs[r];
      m[r] = mn[r];
    }
    #pragma unroll
    for (int ct = 0; ct < 4; ct++) {
      #pragma unroll
      for (int r = 0; r < 4; r++)
        accO[ct][r] *= sc[r];
    }

    // ---- O += P V ----
    const int ihi = lr >> 2, ilo = lr & 3;
    #pragma unroll
    for (int ks = 0; ks < 2; ks++) {
      u16x8 pu;
      #pragma unroll
      for (int e = 0; e < 8; e++)
        pu[e] = Pk[w * 1056 + ihi * 264 + (ks * 32 + lg * 8 + e) * 4 + ilo];
      f16x8 pf = __builtin_bit_cast(f16x8, pu);
      #pragma unroll
      for (int ct = 0; ct < 4; ct++) {
        int c = ct * 16 + lr;
        int ch = (ks * 4 + lg) ^ (c & 7);
        u16x8 vv = *(const u16x8*)&Vs[d][c * 64 + ch * 8];
        accO[ct] = __builtin_amdgcn_mfma_f32_16x16x32_f16(pf, __builtin_bit_cast(f16x8, vv), accO[ct], 0, 0, 0);
      }
    }
    __syncthreads();  // drains staged t+1, guards buffer reuse
  }

  // ---- epilogue: out[b][c][i] = O[i][c] / l[i]; r indexes contiguous i -> float4 ----
  float rl[4];
  #pragma unroll
  for (int r = 0; r < 4; r++) rl[r] = 1.0f / ls[r];
  #pragma unroll
  for (int ct = 0; ct < 4; ct++) {
    f32x4 o;
    #pragma unroll
    for (int r = 0; r < 4; r++) o[r] = accO[ct][r] * rl[r];
    int c = ct * 16 + lr;
    int i = i0 + w * 16 + lg * 4;
    *(f32x4*)(out + ((size_t)b * DIM + c) * NTOK + i) = o;
  }
}

extern "C" void kernel_launch(void* const* d_in, const int* in_sizes, int n_in,
                              void* d_out, int out_size, void* d_ws, size_t ws_size,
                              hipStream_t stream) {
  (void)in_sizes; (void)n_in; (void)out_size; (void)ws_size;
  const float* x  = (const float*)d_in[0];
  // d_in[1] = t  (unused by the reference computation)
  const float* Wq = (const float*)d_in[2];
  const float* bq = (const float*)d_in[3];
  const float* Wk = (const float*)d_in[4];
  const float* bk = (const float*)d_in[5];
  const float* Wv = (const float*)d_in[6];
  const float* bv = (const float*)d_in[7];
  float* out = (float*)d_out;

  unsigned short* Qg = (unsigned short*)d_ws;                 // [4][4096][64] fp16
  unsigned short* Kg = Qg + (size_t)NB * NTOK * DIM;          // [4][4096][64] fp16
  unsigned short* Vg = Kg + (size_t)NB * NTOK * DIM;          // [4][64][4096] fp16

  qkv_proj<<<NB * (NTOK / 64), 256, 0, stream>>>(x, Wq, bq, Wk, bk, Wv, bv, Qg, Kg, Vg);
  attn_fwd<<<NB * (NTOK / 64), 256, 0, stream>>>(Qg, Kg, Vg, out);
}